// Round 1
// baseline (868.620 us; speedup 1.0000x reference)
//
#include <hip/hip_runtime.h>
#include <hip/hip_bf16.h>
#include <math.h>

#define BB 2
#define TT 2048
#define CC 2048
#define NH 16
#define NKV 4
#define HD 128
#define BT (BB*TT)
#define WINDOW 1024

typedef unsigned short u16;
typedef __attribute__((ext_vector_type(8))) short short8;      // 8 bf16 = 4 VGPRs (MFMA A/B frag)
typedef __attribute__((ext_vector_type(8))) unsigned short ushort8;
typedef __attribute__((ext_vector_type(4))) unsigned short ushort4v;
typedef __attribute__((ext_vector_type(4))) float floatx4;     // MFMA C/D frag

static __device__ __forceinline__ u16 f2bf(float f) {
    unsigned u = __builtin_bit_cast(unsigned, f);
    return (u16)((u + 0x7fffu + ((u >> 16) & 1u)) >> 16);   // RNE
}
static __device__ __forceinline__ float bf2f(u16 v) {
    unsigned u = ((unsigned)v) << 16;
    return __builtin_bit_cast(float, u);
}

// ---------------- elementwise cast fp32 -> bf16 ----------------
__global__ void cast_bf16_kernel(const float* __restrict__ in, u16* __restrict__ out, int n4) {
    int i = blockIdx.x * blockDim.x + threadIdx.x;
    if (i >= n4) return;
    floatx4 v = *(const floatx4*)(in + (size_t)i * 4);
    ushort4v o;
    o[0] = f2bf(v[0]); o[1] = f2bf(v[1]); o[2] = f2bf(v[2]); o[3] = f2bf(v[3]);
    *(ushort4v*)(out + (size_t)i * 4) = o;
}

// ---------------- transpose + cast fp32 [R][Cc] -> bf16 [Cc][R] ----------------
__global__ void transpose_cast_f32_kernel(const float* __restrict__ in, u16* __restrict__ out,
                                          int R, int Cc) {
    __shared__ u16 tile[32][33];
    int c0 = blockIdx.x * 32, r0 = blockIdx.y * 32;
    int tx = threadIdx.x, ty = threadIdx.y;   // block (32, 8)
    #pragma unroll
    for (int i = 0; i < 4; i++) {
        int r = r0 + ty + i * 8;
        tile[ty + i * 8][tx] = f2bf(in[(size_t)r * Cc + c0 + tx]);
    }
    __syncthreads();
    #pragma unroll
    for (int i = 0; i < 4; i++) {
        int c = c0 + ty + i * 8;
        out[(size_t)c * R + r0 + tx] = tile[tx][ty + i * 8];
    }
}

// ---------------- transpose bf16 [R][Cc] -> bf16 [Cc][R], batched over z ----------------
__global__ void transpose_bf16_kernel(const u16* __restrict__ in, u16* __restrict__ out,
                                      int R, int Cc) {
    __shared__ u16 tile[32][33];
    int b = blockIdx.z;
    const u16* inb = in + (size_t)b * R * Cc;
    u16* outb = out + (size_t)b * R * Cc;
    int c0 = blockIdx.y * 32, r0 = blockIdx.x * 32;
    int tx = threadIdx.x, ty = threadIdx.y;   // block (32, 8)
    #pragma unroll
    for (int i = 0; i < 4; i++) {
        int r = r0 + ty + i * 8;
        tile[ty + i * 8][tx] = inb[(size_t)r * Cc + c0 + tx];
    }
    __syncthreads();
    #pragma unroll
    for (int i = 0; i < 4; i++) {
        int c = c0 + ty + i * 8;
        outb[(size_t)c * R + r0 + tx] = tile[tx][ty + i * 8];
    }
}

// ---------------- RoPE in-place on [B][T][H][128] bf16, fold scale ----------------
__global__ void rope_kernel(u16* __restrict__ buf, int H, float scale) {
    int idx = blockIdx.x;                 // (b*TT + t)*H + h
    int t = (idx / H) % TT;
    int d = threadIdx.x;                  // 0..127
    u16* p = buf + (size_t)idx * HD;
    float x  = bf2f(p[d]);
    float xp = bf2f(p[d ^ 64]);
    int j = d & 63;
    // inv_timescale = 10000^(-j/64) = 2^(-j*log2(1e4)/64)
    float inv = exp2f(-0.20762050593046f * (float)j);
    float ang = (float)t * inv;
    float s, c;
    sincosf(ang, &s, &c);
    float rot = (d < 64) ? -xp : xp;
    float o = (x * c + rot * s) * scale;
    __syncthreads();                      // all reads done before any write
    p[d] = f2bf(o);
}

// ---------------- GEMM: C[M][N] = A[M][K] * BT[N][K]^T  (bf16 in, fp32 acc) ----------------
template <bool OUT_F32>
__global__ __launch_bounds__(256) void gemm_bt_kernel(const u16* __restrict__ A,
                                                      const u16* __restrict__ Bt,
                                                      void* __restrict__ Cout,
                                                      int M, int N, int K) {
    int lane = threadIdx.x & 63;
    int w = threadIdx.x >> 6;             // 4 waves, 2x2
    int quad = lane >> 4, ln = lane & 15;
    int m0 = blockIdx.y * 64 + (w >> 1) * 32;
    int n0 = blockIdx.x * 64 + (w & 1) * 32;
    floatx4 acc[2][2] = {};
    const u16* a0p = A  + (size_t)(m0 + ln)      * K + quad * 8;
    const u16* a1p = A  + (size_t)(m0 + 16 + ln) * K + quad * 8;
    const u16* b0p = Bt + (size_t)(n0 + ln)      * K + quad * 8;
    const u16* b1p = Bt + (size_t)(n0 + 16 + ln) * K + quad * 8;
    for (int k0 = 0; k0 < K; k0 += 32) {
        short8 a0 = *(const short8*)(a0p + k0);
        short8 a1 = *(const short8*)(a1p + k0);
        short8 b0 = *(const short8*)(b0p + k0);
        short8 b1 = *(const short8*)(b1p + k0);
        acc[0][0] = __builtin_amdgcn_mfma_f32_16x16x32_bf16(a0, b0, acc[0][0], 0, 0, 0);
        acc[0][1] = __builtin_amdgcn_mfma_f32_16x16x32_bf16(a0, b1, acc[0][1], 0, 0, 0);
        acc[1][0] = __builtin_amdgcn_mfma_f32_16x16x32_bf16(a1, b0, acc[1][0], 0, 0, 0);
        acc[1][1] = __builtin_amdgcn_mfma_f32_16x16x32_bf16(a1, b1, acc[1][1], 0, 0, 0);
    }
    // C/D layout: col = ln, row = quad*4 + r   [m89/m91 verified]
    #pragma unroll
    for (int mt = 0; mt < 2; mt++)
      #pragma unroll
      for (int nt = 0; nt < 2; nt++)
        #pragma unroll
        for (int r = 0; r < 4; r++) {
            size_t row = m0 + mt * 16 + quad * 4 + r;
            size_t col = n0 + nt * 16 + ln;
            float v = acc[mt][nt][r];
            if (OUT_F32) ((float*)Cout)[row * N + col] = v;
            else         ((u16*)Cout)[row * N + col] = f2bf(v);
        }
}

// ---------------- flash attention with window + softcap ----------------
// Q: [B][T][NH][HD] bf16 (rope'd, pre-scaled); K: [B][T][NKV][HD] bf16 (rope'd)
// Vt: [B][NKV][HD][T] bf16 ; Enc out: [B][T][NH][HD] bf16
__global__ __launch_bounds__(256) void attn_kernel(const u16* __restrict__ Q,
                                                   const u16* __restrict__ Kb,
                                                   const u16* __restrict__ Vt,
                                                   u16* __restrict__ Enc) {
    __shared__ u16 Kl[32][136];    // 32 keys x 128 d (pad 8 -> stride 272B, 2-way banks)
    __shared__ u16 Vl[128][40];    // V^T tile: 128 d x 32 keys (pad 8)
    __shared__ u16 Pl[4][16][40];  // per-wave P (16 q x 32 s)

    int t0 = blockIdx.x * 64;
    int h  = blockIdx.y;
    int b  = blockIdx.z;
    int kh = h >> 2;               // G=4
    int tid = threadIdx.x;
    int w = tid >> 6, lane = tid & 63, quad = lane >> 4, ln = lane & 15;
    int tw = t0 + w * 16;

    // Q fragments: A[m=ln][k=quad*8+j], 4 k-steps of 32
    short8 qf[4];
    const u16* qbase = Q + (((size_t)b * TT + tw + ln) * NH + h) * HD + quad * 8;
    #pragma unroll
    for (int kk = 0; kk < 4; kk++) qf[kk] = *(const short8*)(qbase + kk * 32);

    floatx4 oacc[8] = {};
    float mrow[4], lrow[4];
    #pragma unroll
    for (int r = 0; r < 4; r++) { mrow[r] = -1e30f; lrow[r] = 0.0f; }

    int s_start = t0 - WINDOW; if (s_start < 0) s_start = 0;
    int s_end = t0 + 64;       // exclusive; all staged keys in [0,T)

    for (int s0 = s_start; s0 < s_end; s0 += 32) {
        __syncthreads();   // protect previous iteration's LDS reads
        {   // stage K tile: 32 rows x 128
            int row = tid >> 3, part = tid & 7;
            const u16* src = Kb + (((size_t)b * TT + s0 + row) * NKV + kh) * HD + part * 16;
            *(ushort8*)(&Kl[row][part * 16])     = *(const ushort8*)(src);
            *(ushort8*)(&Kl[row][part * 16 + 8]) = *(const ushort8*)(src + 8);
        }
        {   // stage V^T tile: 128 d-rows x 32 keys
            int d = tid >> 1, half = tid & 1;
            const u16* src = Vt + (((size_t)b * NKV + kh) * HD + d) * TT + s0 + half * 16;
            *(ushort8*)(&Vl[d][half * 16])     = *(const ushort8*)(src);
            *(ushort8*)(&Vl[d][half * 16 + 8]) = *(const ushort8*)(src + 8);
        }
        __syncthreads();

        // S = Q K^T : two 16-key col tiles
        floatx4 sacc[2] = {};
        #pragma unroll
        for (int nt = 0; nt < 2; nt++)
            #pragma unroll
            for (int kk = 0; kk < 4; kk++) {
                short8 bf = *(const short8*)(&Kl[nt * 16 + ln][kk * 32 + quad * 8]);
                sacc[nt] = __builtin_amdgcn_mfma_f32_16x16x32_bf16(qf[kk], bf, sacc[nt], 0, 0, 0);
            }

        // softcap + window mask + online softmax (rows owned: quad*4+r)
        float pv[2][4]; bool ok[2][4]; float tmax[4];
        #pragma unroll
        for (int r = 0; r < 4; r++) tmax[r] = -1e30f;
        #pragma unroll
        for (int nt = 0; nt < 2; nt++) {
            int s = s0 + nt * 16 + ln;
            #pragma unroll
            for (int r = 0; r < 4; r++) {
                int t = tw + quad * 4 + r;
                float v = 50.0f * tanhf(sacc[nt][r] * 0.02f);
                bool good = (s <= t) && (s >= t - WINDOW);
                ok[nt][r] = good;
                v = good ? v : -1e30f;
                pv[nt][r] = v;
                tmax[r] = fmaxf(tmax[r], v);
            }
        }
        #pragma unroll
        for (int off = 1; off < 16; off <<= 1)
            #pragma unroll
            for (int r = 0; r < 4; r++)
                tmax[r] = fmaxf(tmax[r], __shfl_xor(tmax[r], off));

        float alpha[4], rsum[4];
        #pragma unroll
        for (int r = 0; r < 4; r++) {
            float mnew = fmaxf(mrow[r], tmax[r]);
            alpha[r] = __expf(mrow[r] - mnew);
            mrow[r] = mnew;
        }
        #pragma unroll
        for (int r = 0; r < 4; r++) {
            float s = 0.0f;
            #pragma unroll
            for (int nt = 0; nt < 2; nt++) {
                float p = ok[nt][r] ? __expf(pv[nt][r] - mrow[r]) : 0.0f;
                pv[nt][r] = p;
                s += p;
            }
            rsum[r] = s;
        }
        #pragma unroll
        for (int off = 1; off < 16; off <<= 1)
            #pragma unroll
            for (int r = 0; r < 4; r++) rsum[r] += __shfl_xor(rsum[r], off);
        #pragma unroll
        for (int r = 0; r < 4; r++) lrow[r] = lrow[r] * alpha[r] + rsum[r];

        #pragma unroll
        for (int dt = 0; dt < 8; dt++)
            #pragma unroll
            for (int r = 0; r < 4; r++) oacc[dt][r] *= alpha[r];

        // P -> LDS (C-layout write), read back as A-fragment (wave-local: no barrier)
        #pragma unroll
        for (int nt = 0; nt < 2; nt++)
            #pragma unroll
            for (int r = 0; r < 4; r++)
                Pl[w][quad * 4 + r][nt * 16 + ln] = f2bf(pv[nt][r]);
        short8 pf = *(const short8*)(&Pl[w][ln][quad * 8]);
        #pragma unroll
        for (int dt = 0; dt < 8; dt++) {
            short8 vf = *(const short8*)(&Vl[dt * 16 + ln][quad * 8]);
            oacc[dt] = __builtin_amdgcn_mfma_f32_16x16x32_bf16(pf, vf, oacc[dt], 0, 0, 0);
        }
    }

    // epilogue: normalize + store encoded bf16
    #pragma unroll
    for (int r = 0; r < 4; r++) {
        int t = tw + quad * 4 + r;
        float invl = 1.0f / lrow[r];
        u16* dst = Enc + (((size_t)b * TT + t) * NH + h) * HD;
        #pragma unroll
        for (int dt = 0; dt < 8; dt++)
            dst[dt * 16 + ln] = f2bf(oacc[dt][r] * invl);
    }
}

extern "C" void kernel_launch(void* const* d_in, const int* in_sizes, int n_in,
                              void* d_out, int out_size, void* d_ws, size_t ws_size,
                              hipStream_t stream) {
    const float* x  = (const float*)d_in[0];
    const float* wq = (const float*)d_in[1];
    const float* wk = (const float*)d_in[2];
    const float* wv = (const float*)d_in[3];
    const float* wo = (const float*)d_in[4];
    float* out = (float*)d_out;

    char* ws = (char*)d_ws;
    size_t off = 0;
    auto alloc = [&](size_t bytes) -> void* {
        void* p = ws + off;
        off += (bytes + 255) & ~(size_t)255;
        return p;
    };
    u16* xb  = (u16*)alloc((size_t)BT * CC * 2);          // x bf16 [4096][2048]
    u16* wqT = (u16*)alloc((size_t)CC * CC * 2);          // [2048][2048]
    u16* wkT = (u16*)alloc((size_t)(NKV*HD) * CC * 2);    // [512][2048]
    u16* wvT = (u16*)alloc((size_t)(NKV*HD) * CC * 2);
    u16* woT = (u16*)alloc((size_t)CC * CC * 2);
    u16* Qb  = (u16*)alloc((size_t)BT * NH * HD * 2);     // [4096][2048]
    u16* Kb  = (u16*)alloc((size_t)BT * NKV * HD * 2);    // [4096][512]
    u16* Vb  = (u16*)alloc((size_t)BT * NKV * HD * 2);
    u16* VtT = (u16*)alloc((size_t)BT * NKV * HD * 2);    // [B][NKV][HD][T]
    u16* Enc = (u16*)alloc((size_t)BT * NH * HD * 2);

    // 1) casts / weight transposes
    cast_bf16_kernel<<<(BT * CC / 4 + 255) / 256, 256, 0, stream>>>(x, xb, BT * CC / 4);
    dim3 tb(32, 8);
    transpose_cast_f32_kernel<<<dim3(CC / 32, CC / 32), tb, 0, stream>>>(wq, wqT, CC, CC);
    transpose_cast_f32_kernel<<<dim3(NKV * HD / 32, CC / 32), tb, 0, stream>>>(wk, wkT, CC, NKV * HD);
    transpose_cast_f32_kernel<<<dim3(NKV * HD / 32, CC / 32), tb, 0, stream>>>(wv, wvT, CC, NKV * HD);
    transpose_cast_f32_kernel<<<dim3(CC / 32, CC / 32), tb, 0, stream>>>(wo, woT, CC, CC);

    // 2) QKV projections (bf16 out)
    gemm_bt_kernel<false><<<dim3(CC / 64, BT / 64), 256, 0, stream>>>(xb, wqT, Qb, BT, CC, CC);
    gemm_bt_kernel<false><<<dim3(NKV * HD / 64, BT / 64), 256, 0, stream>>>(xb, wkT, Kb, BT, NKV * HD, CC);
    gemm_bt_kernel<false><<<dim3(NKV * HD / 64, BT / 64), 256, 0, stream>>>(xb, wvT, Vb, BT, NKV * HD, CC);

    // 3) RoPE (scale folded into Q)
    rope_kernel<<<BT * NH, HD, 0, stream>>>(Qb, NH, 0.08838834764831845f);
    rope_kernel<<<BT * NKV, HD, 0, stream>>>(Kb, NKV, 1.0f);

    // 4) V -> V^T per (b): [T][512] -> [512][T]
    transpose_bf16_kernel<<<dim3(TT / 32, NKV * HD / 32, BB), tb, 0, stream>>>(Vb, VtT, TT, NKV * HD);

    // 5) flash attention
    attn_kernel<<<dim3(TT / 64, NH, BB), 256, 0, stream>>>(Qb, Kb, VtT, Enc);

    // 6) output projection (fp32 out)
    gemm_bt_kernel<true><<<dim3(CC / 64, BT / 64), 256, 0, stream>>>(Enc, woT, out, BT, CC, CC);
}

// Round 2
// 455.190 us; speedup vs baseline: 1.9083x; 1.9083x over previous
//
#include <hip/hip_runtime.h>
#include <hip/hip_bf16.h>
#include <math.h>

#define BB 2
#define TT 2048
#define CC 2048
#define NH 16
#define NKV 4
#define HD 128
#define BT (BB*TT)
#define WINDOW 1024

typedef unsigned short u16;
typedef unsigned int u32;
typedef __attribute__((ext_vector_type(8))) short short8;      // 8 bf16 = 4 VGPRs (MFMA A/B frag)
typedef __attribute__((ext_vector_type(8))) unsigned short ushort8;
typedef __attribute__((ext_vector_type(4))) unsigned short ushort4v;
typedef __attribute__((ext_vector_type(4))) float floatx4;     // MFMA C/D frag

typedef const __attribute__((address_space(1))) u32* gas_ptr;
typedef __attribute__((address_space(3))) u32* las_ptr;

static __device__ __forceinline__ u16 f2bf(float f) {
    unsigned u = __builtin_bit_cast(unsigned, f);
    return (u16)((u + 0x7fffu + ((u >> 16) & 1u)) >> 16);   // RNE
}
static __device__ __forceinline__ float bf2f(u16 v) {
    unsigned u = ((unsigned)v) << 16;
    return __builtin_bit_cast(float, u);
}

// ---------------- elementwise cast fp32 -> bf16 ----------------
__global__ void cast_bf16_kernel(const float* __restrict__ in, u16* __restrict__ out, int n4) {
    int i = blockIdx.x * blockDim.x + threadIdx.x;
    if (i >= n4) return;
    floatx4 v = *(const floatx4*)(in + (size_t)i * 4);
    ushort4v o;
    o[0] = f2bf(v[0]); o[1] = f2bf(v[1]); o[2] = f2bf(v[2]); o[3] = f2bf(v[3]);
    *(ushort4v*)(out + (size_t)i * 4) = o;
}

// ---------------- transpose + cast fp32 [R][Cc] -> bf16 [Cc][R] ----------------
__global__ void transpose_cast_f32_kernel(const float* __restrict__ in, u16* __restrict__ out,
                                          int R, int Cc) {
    __shared__ u16 tile[32][33];
    int c0 = blockIdx.x * 32, r0 = blockIdx.y * 32;
    int tx = threadIdx.x, ty = threadIdx.y;   // block (32, 8)
    #pragma unroll
    for (int i = 0; i < 4; i++) {
        int r = r0 + ty + i * 8;
        tile[ty + i * 8][tx] = f2bf(in[(size_t)r * Cc + c0 + tx]);
    }
    __syncthreads();
    #pragma unroll
    for (int i = 0; i < 4; i++) {
        int c = c0 + ty + i * 8;
        out[(size_t)c * R + r0 + tx] = tile[tx][ty + i * 8];
    }
}

// ---------------- strided transpose bf16: in[r][colOff + c] (stride inStride) -> out [Cc][R], batched z ----------------
__global__ void transpose_bf16_kernel(const u16* __restrict__ in, u16* __restrict__ out,
                                      int R, int Cc, int inStride, int colOff,
                                      size_t inBatchStride, size_t outBatchStride) {
    __shared__ u16 tile[32][33];
    int b = blockIdx.z;
    const u16* inb = in + (size_t)b * inBatchStride;
    u16* outb = out + (size_t)b * outBatchStride;
    int c0 = blockIdx.y * 32, r0 = blockIdx.x * 32;
    int tx = threadIdx.x, ty = threadIdx.y;   // block (32, 8)
    #pragma unroll
    for (int i = 0; i < 4; i++) {
        int r = r0 + ty + i * 8;
        tile[ty + i * 8][tx] = inb[(size_t)r * inStride + colOff + c0 + tx];
    }
    __syncthreads();
    #pragma unroll
    for (int i = 0; i < 4; i++) {
        int c = c0 + ty + i * 8;
        outb[(size_t)c * R + r0 + tx] = tile[tx][ty + i * 8];
    }
}

// ---------------- RoPE in-place on rows of `rowStride` elems, H heads x 128, fold scale ----------------
__global__ void rope_kernel(u16* __restrict__ buf, int H, int rowStride, float scale) {
    int idx = blockIdx.x;                 // bt*H + h
    int bt = idx / H, h = idx - bt * H;
    int t = bt % TT;
    int d = threadIdx.x;                  // 0..127
    u16* p = buf + (size_t)bt * rowStride + h * HD;
    float x  = bf2f(p[d]);
    float xp = bf2f(p[d ^ 64]);
    int j = d & 63;
    // inv_timescale = 10000^(-j/64) = 2^(-j*log2(1e4)/64)
    float inv = exp2f(-0.20762050593046f * (float)j);
    float ang = (float)t * inv;
    float s, c;
    sincosf(ang, &s, &c);
    float rot = (d < 64) ? -xp : xp;
    float o = (x * c + rot * s) * scale;
    __syncthreads();                      // all reads done before any write
    p[d] = f2bf(o);
}

// ---------------- m97-style GEMM: C[M][N] = A[M][K] * Bt[N][K]^T (bf16 in, fp32 acc) ----------------
// 128x128 tile, BK=32, 4 waves (2x2 of 64x64), global_load_lds width-16 staging.
template <bool OUT_F32>
__global__ __launch_bounds__(256) void gemm128_kernel(const u16* __restrict__ A,
                                                      const u16* __restrict__ Bt,
                                                      void* __restrict__ Cout,
                                                      int M, int N, int K) {
    __shared__ alignas(16) u16 As[128 * 32];   // row-major [128][32], NO padding (lds-dma layout)
    __shared__ alignas(16) u16 Bs[128 * 32];
    int tid = threadIdx.x;
    int w = tid >> 6, lane = tid & 63, quad = lane >> 4, ln = lane & 15;
    int m0 = blockIdx.y * 128;
    int n0 = blockIdx.x * 128;
    int wm = (w >> 1) * 64;        // wave sub-tile origin inside 128x128
    int wn = (w & 1) * 64;

    // staging map: chunk j (0..1): byte offset o = (w*2+j)*1024 + lane*16
    // -> tile row = o/64, k-chunk = (o%64)/16. LDS dest = As + o (wave-uniform base + lane*16).
    int o0 = (w * 2) * 1024 + lane * 16;
    int row0 = o0 >> 6, kc0 = (o0 & 63) >> 4;
    int o1 = o0 + 1024;
    int row1 = o1 >> 6, kc1 = (o1 & 63) >> 4;
    const u16* gA0 = A  + (size_t)(m0 + row0) * K + kc0 * 8;
    const u16* gA1 = A  + (size_t)(m0 + row1) * K + kc1 * 8;
    const u16* gB0 = Bt + (size_t)(n0 + row0) * K + kc0 * 8;
    const u16* gB1 = Bt + (size_t)(n0 + row1) * K + kc1 * 8;
    u16* lA0 = As + (w * 2) * 512;       // u16 units: 1024 B = 512 elems
    u16* lA1 = As + (w * 2 + 1) * 512;
    u16* lB0 = Bs + (w * 2) * 512;
    u16* lB1 = Bs + (w * 2 + 1) * 512;

    floatx4 acc[4][4] = {};

    for (int k0 = 0; k0 < K; k0 += 32) {
        __syncthreads();   // previous iteration's LDS reads complete
        __builtin_amdgcn_global_load_lds((gas_ptr)(gA0 + k0), (las_ptr)lA0, 16, 0, 0);
        __builtin_amdgcn_global_load_lds((gas_ptr)(gA1 + k0), (las_ptr)lA1, 16, 0, 0);
        __builtin_amdgcn_global_load_lds((gas_ptr)(gB0 + k0), (las_ptr)lB0, 16, 0, 0);
        __builtin_amdgcn_global_load_lds((gas_ptr)(gB1 + k0), (las_ptr)lB1, 16, 0, 0);
        __syncthreads();   // staging visible (compiler inserts vmcnt(0))

        short8 af[4], bf[4];
        #pragma unroll
        for (int mt = 0; mt < 4; mt++)
            af[mt] = *(const short8*)(As + (wm + mt * 16 + ln) * 32 + quad * 8);
        #pragma unroll
        for (int nt = 0; nt < 4; nt++)
            bf[nt] = *(const short8*)(Bs + (wn + nt * 16 + ln) * 32 + quad * 8);
        #pragma unroll
        for (int mt = 0; mt < 4; mt++)
            #pragma unroll
            for (int nt = 0; nt < 4; nt++)
                acc[mt][nt] = __builtin_amdgcn_mfma_f32_16x16x32_bf16(af[mt], bf[nt], acc[mt][nt], 0, 0, 0);
    }

    // C/D layout: col = ln, row = quad*4 + r   [m89/m91 verified]
    #pragma unroll
    for (int mt = 0; mt < 4; mt++)
      #pragma unroll
      for (int nt = 0; nt < 4; nt++)
        #pragma unroll
        for (int r = 0; r < 4; r++) {
            size_t row = m0 + wm + mt * 16 + quad * 4 + r;
            size_t col = n0 + wn + nt * 16 + ln;
            float v = acc[mt][nt][r];
            if (OUT_F32) ((float*)Cout)[row * N + col] = v;
            else         ((u16*)Cout)[row * N + col] = f2bf(v);
        }
}

// ---------------- flash attention with window + softcap ----------------
// Q: [B][T][NH*HD] bf16 (rope'd, pre-scaled); KV: [B][T][1024] bf16 (cols 0-511 = K rope'd, 512-1023 = V)
// Vt: [B][NKV][HD][T] bf16 ; Enc out: [B][T][NH][HD] bf16
__global__ __launch_bounds__(256) void attn_kernel(const u16* __restrict__ Q,
                                                   const u16* __restrict__ KV,
                                                   const u16* __restrict__ Vt,
                                                   u16* __restrict__ Enc) {
    __shared__ u16 Kl[32][136];    // 32 keys x 128 d (pad 8)
    __shared__ u16 Vl[128][40];    // V^T tile: 128 d x 32 keys (pad 8)
    __shared__ u16 Pl[4][16][40];  // per-wave P (16 q x 32 s)

    int t0 = blockIdx.x * 64;
    int h  = blockIdx.y;
    int b  = blockIdx.z;
    int kh = h >> 2;               // G=4
    int tid = threadIdx.x;
    int w = tid >> 6, lane = tid & 63, quad = lane >> 4, ln = lane & 15;
    int tw = t0 + w * 16;

    // Q fragments: A[m=ln][k=quad*8+j], 4 k-steps of 32
    short8 qf[4];
    const u16* qbase = Q + (((size_t)b * TT + tw + ln) * NH + h) * HD + quad * 8;
    #pragma unroll
    for (int kk = 0; kk < 4; kk++) qf[kk] = *(const short8*)(qbase + kk * 32);

    floatx4 oacc[8] = {};
    float mrow[4], lrow[4];
    #pragma unroll
    for (int r = 0; r < 4; r++) { mrow[r] = -1e30f; lrow[r] = 0.0f; }

    int s_start = t0 - WINDOW; if (s_start < 0) s_start = 0;
    int s_end = t0 + 64;       // exclusive

    for (int s0 = s_start; s0 < s_end; s0 += 32) {
        __syncthreads();   // protect previous iteration's LDS reads
        {   // stage K tile: 32 rows x 128 (from KV cols kh*128..)
            int row = tid >> 3, part = tid & 7;
            const u16* src = KV + ((size_t)b * TT + s0 + row) * (2 * NKV * HD) + kh * HD + part * 16;
            *(ushort8*)(&Kl[row][part * 16])     = *(const ushort8*)(src);
            *(ushort8*)(&Kl[row][part * 16 + 8]) = *(const ushort8*)(src + 8);
        }
        {   // stage V^T tile: 128 d-rows x 32 keys
            int d = tid >> 1, half = tid & 1;
            const u16* src = Vt + (((size_t)b * NKV + kh) * HD + d) * TT + s0 + half * 16;
            *(ushort8*)(&Vl[d][half * 16])     = *(const ushort8*)(src);
            *(ushort8*)(&Vl[d][half * 16 + 8]) = *(const ushort8*)(src + 8);
        }
        __syncthreads();

        // S = Q K^T : two 16-key col tiles
        floatx4 sacc[2] = {};
        #pragma unroll
        for (int nt = 0; nt < 2; nt++)
            #pragma unroll
            for (int kk = 0; kk < 4; kk++) {
                short8 bfr = *(const short8*)(&Kl[nt * 16 + ln][kk * 32 + quad * 8]);
                sacc[nt] = __builtin_amdgcn_mfma_f32_16x16x32_bf16(qf[kk], bfr, sacc[nt], 0, 0, 0);
            }

        // softcap + window mask + online softmax (rows owned: quad*4+r)
        float pv[2][4]; bool ok[2][4]; float tmax[4];
        #pragma unroll
        for (int r = 0; r < 4; r++) tmax[r] = -1e30f;
        #pragma unroll
        for (int nt = 0; nt < 2; nt++) {
            int s = s0 + nt * 16 + ln;
            #pragma unroll
            for (int r = 0; r < 4; r++) {
                int t = tw + quad * 4 + r;
                float v = 50.0f * tanhf(sacc[nt][r] * 0.02f);
                bool good = (s <= t) && (s >= t - WINDOW);
                ok[nt][r] = good;
                v = good ? v : -1e30f;
                pv[nt][r] = v;
                tmax[r] = fmaxf(tmax[r], v);
            }
        }
        #pragma unroll
        for (int off = 1; off < 16; off <<= 1)
            #pragma unroll
            for (int r = 0; r < 4; r++)
                tmax[r] = fmaxf(tmax[r], __shfl_xor(tmax[r], off));

        float alpha[4], rsum[4];
        #pragma unroll
        for (int r = 0; r < 4; r++) {
            float mnew = fmaxf(mrow[r], tmax[r]);
            alpha[r] = __expf(mrow[r] - mnew);
            mrow[r] = mnew;
        }
        #pragma unroll
        for (int r = 0; r < 4; r++) {
            float s = 0.0f;
            #pragma unroll
            for (int nt = 0; nt < 2; nt++) {
                float p = ok[nt][r] ? __expf(pv[nt][r] - mrow[r]) : 0.0f;
                pv[nt][r] = p;
                s += p;
            }
            rsum[r] = s;
        }
        #pragma unroll
        for (int off = 1; off < 16; off <<= 1)
            #pragma unroll
            for (int r = 0; r < 4; r++) rsum[r] += __shfl_xor(rsum[r], off);
        #pragma unroll
        for (int r = 0; r < 4; r++) lrow[r] = lrow[r] * alpha[r] + rsum[r];

        #pragma unroll
        for (int dt = 0; dt < 8; dt++)
            #pragma unroll
            for (int r = 0; r < 4; r++) oacc[dt][r] *= alpha[r];

        // P -> LDS (C-layout write), read back as A-fragment (wave-local: no barrier)
        #pragma unroll
        for (int nt = 0; nt < 2; nt++)
            #pragma unroll
            for (int r = 0; r < 4; r++)
                Pl[w][quad * 4 + r][nt * 16 + ln] = f2bf(pv[nt][r]);
        short8 pf = *(const short8*)(&Pl[w][ln][quad * 8]);
        #pragma unroll
        for (int dt = 0; dt < 8; dt++) {
            short8 vf = *(const short8*)(&Vl[dt * 16 + ln][quad * 8]);
            oacc[dt] = __builtin_amdgcn_mfma_f32_16x16x32_bf16(pf, vf, oacc[dt], 0, 0, 0);
        }
    }

    // epilogue: normalize + store encoded bf16
    #pragma unroll
    for (int r = 0; r < 4; r++) {
        int t = tw + quad * 4 + r;
        float invl = 1.0f / lrow[r];
        u16* dst = Enc + (((size_t)b * TT + t) * NH + h) * HD;
        #pragma unroll
        for (int dt = 0; dt < 8; dt++)
            dst[dt * 16 + ln] = f2bf(oacc[dt][r] * invl);
    }
}

extern "C" void kernel_launch(void* const* d_in, const int* in_sizes, int n_in,
                              void* d_out, int out_size, void* d_ws, size_t ws_size,
                              hipStream_t stream) {
    const float* x  = (const float*)d_in[0];
    const float* wq = (const float*)d_in[1];
    const float* wk = (const float*)d_in[2];
    const float* wv = (const float*)d_in[3];
    const float* wo = (const float*)d_in[4];
    float* out = (float*)d_out;

    char* ws = (char*)d_ws;
    size_t off = 0;
    auto alloc = [&](size_t bytes) -> void* {
        void* p = ws + off;
        off += (bytes + 255) & ~(size_t)255;
        return p;
    };
    u16* xb   = (u16*)alloc((size_t)BT * CC * 2);           // x bf16 [4096][2048]
    u16* wqT  = (u16*)alloc((size_t)CC * CC * 2);           // [2048][2048]
    u16* wkvT = (u16*)alloc((size_t)(2*NKV*HD) * CC * 2);   // [1024][2048]: K rows 0-511, V rows 512-1023
    u16* woT  = (u16*)alloc((size_t)CC * CC * 2);
    u16* Qb   = (u16*)alloc((size_t)BT * NH * HD * 2);      // [4096][2048]
    u16* KVb  = (u16*)alloc((size_t)BT * 2 * NKV * HD * 2); // [4096][1024]
    u16* VtT  = (u16*)alloc((size_t)BT * NKV * HD * 2);     // [B][NKV][HD][T]
    u16* Enc  = (u16*)alloc((size_t)BT * NH * HD * 2);

    // 1) casts / weight transposes
    cast_bf16_kernel<<<(BT * CC / 4 + 255) / 256, 256, 0, stream>>>(x, xb, BT * CC / 4);
    dim3 tb(32, 8);
    transpose_cast_f32_kernel<<<dim3(CC / 32, CC / 32), tb, 0, stream>>>(wq, wqT, CC, CC);
    transpose_cast_f32_kernel<<<dim3(NKV * HD / 32, CC / 32), tb, 0, stream>>>(wk, wkvT, CC, NKV * HD);
    transpose_cast_f32_kernel<<<dim3(NKV * HD / 32, CC / 32), tb, 0, stream>>>(wv, wkvT + (size_t)(NKV * HD) * CC, CC, NKV * HD);
    transpose_cast_f32_kernel<<<dim3(CC / 32, CC / 32), tb, 0, stream>>>(wo, woT, CC, CC);

    // 2) projections: Q (N=2048) and merged KV (N=1024)
    gemm128_kernel<false><<<dim3(CC / 128, BT / 128), 256, 0, stream>>>(xb, wqT, Qb, BT, CC, CC);
    gemm128_kernel<false><<<dim3(2 * NKV * HD / 128, BT / 128), 256, 0, stream>>>(xb, wkvT, KVb, BT, 2 * NKV * HD, CC);

    // 3) RoPE (scale folded into Q); K lives in first 512 cols of KVb rows (stride 1024)
    rope_kernel<<<BT * NH, HD, 0, stream>>>(Qb, NH, NH * HD, 0.08838834764831845f);
    rope_kernel<<<BT * NKV, HD, 0, stream>>>(KVb, NKV, 2 * NKV * HD, 1.0f);

    // 4) V -> V^T per batch: KVb rows [T][1024] cols 512.. -> [512][T]
    transpose_bf16_kernel<<<dim3(TT / 32, NKV * HD / 32, BB), tb, 0, stream>>>(
        KVb, VtT, TT, NKV * HD, 2 * NKV * HD, NKV * HD,
        (size_t)TT * 2 * NKV * HD, (size_t)NKV * HD * TT);

    // 5) flash attention
    attn_kernel<<<dim3(TT / 64, NH, BB), 256, 0, stream>>>(Qb, KVb, VtT, Enc);

    // 6) output projection (fp32 out)
    gemm128_kernel<true><<<dim3(CC / 128, BT / 128), 256, 0, stream>>>(Enc, woT, out, BT, CC, CC);
}

// Round 3
// 391.297 us; speedup vs baseline: 2.2198x; 1.1633x over previous
//
#include <hip/hip_runtime.h>
#include <hip/hip_bf16.h>
#include <math.h>

#define BB 2
#define TT 2048
#define CC 2048
#define NH 16
#define NKV 4
#define HD 128
#define BT (BB*TT)
#define WINDOW 1024

typedef unsigned short u16;
typedef unsigned int u32;
typedef __attribute__((ext_vector_type(8))) short short8;      // 8 bf16 = 4 VGPRs (MFMA A/B frag)
typedef __attribute__((ext_vector_type(8))) unsigned short ushort8;
typedef __attribute__((ext_vector_type(4))) unsigned short ushort4v;
typedef __attribute__((ext_vector_type(4))) float floatx4;     // MFMA C/D frag

typedef const __attribute__((address_space(1))) u32* gas_ptr;
typedef __attribute__((address_space(3))) u32* las_ptr;

static __device__ __forceinline__ u16 f2bf(float f) {
    unsigned u = __builtin_bit_cast(unsigned, f);
    return (u16)((u + 0x7fffu + ((u >> 16) & 1u)) >> 16);   // RNE
}
static __device__ __forceinline__ float bf2f(u16 v) {
    unsigned u = ((unsigned)v) << 16;
    return __builtin_bit_cast(float, u);
}

// fused softcap + exp: exp(50*tanh(s/50)) = exp2(72.1348 - 144.2695/(1+exp2(s*0.0577078)))
// saturates to e^{+-50} for large |s|; no NaN/overflow possible.
static __device__ __forceinline__ float softcap_exp(float s) {
    float z = __builtin_amdgcn_exp2f(s * 0.05770780163f);
    float r = __builtin_amdgcn_rcpf(1.0f + z);
    return __builtin_amdgcn_exp2f(fmaf(-144.269504089f, r, 72.1347520444f));
}

// ---------------- elementwise cast fp32 -> bf16 ----------------
__global__ void cast_bf16_kernel(const float* __restrict__ in, u16* __restrict__ out, int n4) {
    int i = blockIdx.x * blockDim.x + threadIdx.x;
    if (i >= n4) return;
    floatx4 v = *(const floatx4*)(in + (size_t)i * 4);
    ushort4v o;
    o[0] = f2bf(v[0]); o[1] = f2bf(v[1]); o[2] = f2bf(v[2]); o[3] = f2bf(v[3]);
    *(ushort4v*)(out + (size_t)i * 4) = o;
}

// ---------------- transpose + cast fp32 [R][Cc] -> bf16 [Cc][R] ----------------
__global__ void transpose_cast_f32_kernel(const float* __restrict__ in, u16* __restrict__ out,
                                          int R, int Cc) {
    __shared__ u16 tile[32][33];
    int c0 = blockIdx.x * 32, r0 = blockIdx.y * 32;
    int tx = threadIdx.x, ty = threadIdx.y;   // block (32, 8)
    #pragma unroll
    for (int i = 0; i < 4; i++) {
        int r = r0 + ty + i * 8;
        tile[ty + i * 8][tx] = f2bf(in[(size_t)r * Cc + c0 + tx]);
    }
    __syncthreads();
    #pragma unroll
    for (int i = 0; i < 4; i++) {
        int c = c0 + ty + i * 8;
        out[(size_t)c * R + r0 + tx] = tile[tx][ty + i * 8];
    }
}

// ---------------- strided transpose bf16: in[r][colOff + c] (stride inStride) -> out [Cc][R], batched z ----------------
__global__ void transpose_bf16_kernel(const u16* __restrict__ in, u16* __restrict__ out,
                                      int R, int Cc, int inStride, int colOff,
                                      size_t inBatchStride, size_t outBatchStride) {
    __shared__ u16 tile[32][33];
    int b = blockIdx.z;
    const u16* inb = in + (size_t)b * inBatchStride;
    u16* outb = out + (size_t)b * outBatchStride;
    int c0 = blockIdx.y * 32, r0 = blockIdx.x * 32;
    int tx = threadIdx.x, ty = threadIdx.y;   // block (32, 8)
    #pragma unroll
    for (int i = 0; i < 4; i++) {
        int r = r0 + ty + i * 8;
        tile[ty + i * 8][tx] = inb[(size_t)r * inStride + colOff + c0 + tx];
    }
    __syncthreads();
    #pragma unroll
    for (int i = 0; i < 4; i++) {
        int c = c0 + ty + i * 8;
        outb[(size_t)c * R + r0 + tx] = tile[tx][ty + i * 8];
    }
}

// ---------------- RoPE in-place on rows of `rowStride` elems, H heads x 128, fold scale ----------------
__global__ void rope_kernel(u16* __restrict__ buf, int H, int rowStride, float scale) {
    int idx = blockIdx.x;                 // bt*H + h
    int bt = idx / H, h = idx - bt * H;
    int t = bt % TT;
    int d = threadIdx.x;                  // 0..127
    u16* p = buf + (size_t)bt * rowStride + h * HD;
    float x  = bf2f(p[d]);
    float xp = bf2f(p[d ^ 64]);
    int j = d & 63;
    float inv = exp2f(-0.20762050593046f * (float)j);   // 10000^(-j/64)
    float ang = (float)t * inv;
    float s, c;
    sincosf(ang, &s, &c);
    float rot = (d < 64) ? -xp : xp;
    float o = (x * c + rot * s) * scale;
    __syncthreads();                      // all reads done before any write
    p[d] = f2bf(o);
}

// ---------------- m97-style GEMM: C[M][N] = A[M][K] * Bt[N][K]^T (bf16 in, fp32 acc) ----------------
template <bool OUT_F32>
__global__ __launch_bounds__(256) void gemm128_kernel(const u16* __restrict__ A,
                                                      const u16* __restrict__ Bt,
                                                      void* __restrict__ Cout,
                                                      int M, int N, int K) {
    __shared__ alignas(16) u16 As[128 * 32];   // row-major [128][32], NO padding (lds-dma layout)
    __shared__ alignas(16) u16 Bs[128 * 32];
    int tid = threadIdx.x;
    int w = tid >> 6, lane = tid & 63, quad = lane >> 4, ln = lane & 15;
    int m0 = blockIdx.y * 128;
    int n0 = blockIdx.x * 128;
    int wm = (w >> 1) * 64;
    int wn = (w & 1) * 64;

    int o0 = (w * 2) * 1024 + lane * 16;
    int row0 = o0 >> 6, kc0 = (o0 & 63) >> 4;
    int o1 = o0 + 1024;
    int row1 = o1 >> 6, kc1 = (o1 & 63) >> 4;
    const u16* gA0 = A  + (size_t)(m0 + row0) * K + kc0 * 8;
    const u16* gA1 = A  + (size_t)(m0 + row1) * K + kc1 * 8;
    const u16* gB0 = Bt + (size_t)(n0 + row0) * K + kc0 * 8;
    const u16* gB1 = Bt + (size_t)(n0 + row1) * K + kc1 * 8;
    u16* lA0 = As + (w * 2) * 512;
    u16* lA1 = As + (w * 2 + 1) * 512;
    u16* lB0 = Bs + (w * 2) * 512;
    u16* lB1 = Bs + (w * 2 + 1) * 512;

    floatx4 acc[4][4] = {};

    for (int k0 = 0; k0 < K; k0 += 32) {
        __syncthreads();
        __builtin_amdgcn_global_load_lds((gas_ptr)(gA0 + k0), (las_ptr)lA0, 16, 0, 0);
        __builtin_amdgcn_global_load_lds((gas_ptr)(gA1 + k0), (las_ptr)lA1, 16, 0, 0);
        __builtin_amdgcn_global_load_lds((gas_ptr)(gB0 + k0), (las_ptr)lB0, 16, 0, 0);
        __builtin_amdgcn_global_load_lds((gas_ptr)(gB1 + k0), (las_ptr)lB1, 16, 0, 0);
        __syncthreads();

        short8 af[4], bf[4];
        #pragma unroll
        for (int mt = 0; mt < 4; mt++)
            af[mt] = *(const short8*)(As + (wm + mt * 16 + ln) * 32 + quad * 8);
        #pragma unroll
        for (int nt = 0; nt < 4; nt++)
            bf[nt] = *(const short8*)(Bs + (wn + nt * 16 + ln) * 32 + quad * 8);
        #pragma unroll
        for (int mt = 0; mt < 4; mt++)
            #pragma unroll
            for (int nt = 0; nt < 4; nt++)
                acc[mt][nt] = __builtin_amdgcn_mfma_f32_16x16x32_bf16(af[mt], bf[nt], acc[mt][nt], 0, 0, 0);
    }

    #pragma unroll
    for (int mt = 0; mt < 4; mt++)
      #pragma unroll
      for (int nt = 0; nt < 4; nt++)
        #pragma unroll
        for (int r = 0; r < 4; r++) {
            size_t row = m0 + wm + mt * 16 + quad * 4 + r;
            size_t col = n0 + wn + nt * 16 + ln;
            float v = acc[mt][nt][r];
            if (OUT_F32) ((float*)Cout)[row * N + col] = v;
            else         ((u16*)Cout)[row * N + col] = f2bf(v);
        }
}

// ---------------- flash attention: fixed-max streaming softmax, dbuf DMA staging ----------------
// Q: [B][T][NH*HD] bf16 (rope'd, pre-scaled); KV: [B][T][1024] bf16 (cols 0-511 = K rope'd)
// Vt: [B][NKV][HD][T] bf16 ; Enc out: [B][T][NH][HD] bf16
__global__ __launch_bounds__(256) void attn_kernel(const u16* __restrict__ Q,
                                                   const u16* __restrict__ KV,
                                                   const u16* __restrict__ Vt,
                                                   u16* __restrict__ Enc) {
    __shared__ alignas(16) u16 Kl[2][32 * 128];  // swizzled: LDS[row][c^ (row&15)] = K[row][c], 16B chunks
    __shared__ alignas(16) u16 Vl[2][128 * 32];  // [d][key], 64B rows (conflict-free for B-frag reads)
    __shared__ alignas(16) u16 Pl[4][16][40];    // per-wave P (16 q x 32 s), pad 8

    int t0 = ((int)gridDim.x - 1 - (int)blockIdx.x) * 64;   // long blocks first
    int h  = blockIdx.y;
    int b  = blockIdx.z;
    int kh = h >> 2;               // G=4
    int tid = threadIdx.x;
    int w = tid >> 6, lane = tid & 63, quad = lane >> 4, ln = lane & 15;
    int tw = t0 + w * 16;

    // Q fragments: A[m=ln][k=quad*8+j], 4 k-steps of 32
    short8 qf[4];
    const u16* qbase = Q + (((size_t)b * TT + tw + ln) * NH + h) * HD + quad * 8;
    #pragma unroll
    for (int kk = 0; kk < 4; kk++) qf[kk] = *(const short8*)(qbase + kk * 32);

    // ones B-fragment (bf16 1.0) for the row-sum MFMA
    short8 ones;
    #pragma unroll
    for (int i = 0; i < 8; i++) ones[i] = (short)0x3F80;

    floatx4 oacc[9] = {};   // [0..7]: d-tiles of O (unnormalized); [8]: row sums l

    // staging source pointers (per-lane), chunk j in {0,1}: LDS bytes [(w*2+j)*1024, +1024)
    int oj0 = (w * 2) * 1024 + lane * 16;
    int oj1 = oj0 + 1024;
    int kr0 = oj0 >> 8, kc0 = ((oj0 >> 4) & 15) ^ (kr0 & 15);
    int kr1 = oj1 >> 8, kc1 = ((oj1 >> 4) & 15) ^ (kr1 & 15);
    const u16* gK0 = KV + ((size_t)b * TT + kr0) * (2 * NKV * HD) + kh * HD + kc0 * 8;
    const u16* gK1 = KV + ((size_t)b * TT + kr1) * (2 * NKV * HD) + kh * HD + kc1 * 8;
    int vr0 = oj0 >> 6, vc0 = (oj0 >> 4) & 3;
    int vr1 = oj1 >> 6, vc1 = (oj1 >> 4) & 3;
    const u16* gV0 = Vt + (((size_t)b * NKV + kh) * HD + vr0) * TT + vc0 * 8;
    const u16* gV1 = Vt + (((size_t)b * NKV + kh) * HD + vr1) * TT + vc1 * 8;
    int lo0 = (w * 2) * 512, lo1 = lo0 + 512;   // u16 offsets into an 8KB tile

    int s_start = t0 - WINDOW; if (s_start < 0) s_start = 0;
    int s_end = t0 + 64;       // exclusive

    // prologue: stage first tile into buf 0
    {
        size_t ks = (size_t)s_start * (2 * NKV * HD);
        __builtin_amdgcn_global_load_lds((gas_ptr)(gK0 + ks), (las_ptr)(&Kl[0][lo0]), 16, 0, 0);
        __builtin_amdgcn_global_load_lds((gas_ptr)(gK1 + ks), (las_ptr)(&Kl[0][lo1]), 16, 0, 0);
        __builtin_amdgcn_global_load_lds((gas_ptr)(gV0 + s_start), (las_ptr)(&Vl[0][lo0]), 16, 0, 0);
        __builtin_amdgcn_global_load_lds((gas_ptr)(gV1 + s_start), (las_ptr)(&Vl[0][lo1]), 16, 0, 0);
    }

    int buf = 0;
    for (int s0 = s_start; s0 < s_end; s0 += 32) {
        __syncthreads();   // DMA for `buf` complete (vmcnt drain) + prev reads done
        int sn = s0 + 32;
        if (sn < s_end) {  // prefetch next tile into buf^1 (overlaps this iteration's compute)
            int nb = buf ^ 1;
            size_t ks = (size_t)sn * (2 * NKV * HD);
            __builtin_amdgcn_global_load_lds((gas_ptr)(gK0 + ks), (las_ptr)(&Kl[nb][lo0]), 16, 0, 0);
            __builtin_amdgcn_global_load_lds((gas_ptr)(gK1 + ks), (las_ptr)(&Kl[nb][lo1]), 16, 0, 0);
            __builtin_amdgcn_global_load_lds((gas_ptr)(gV0 + sn), (las_ptr)(&Vl[nb][lo0]), 16, 0, 0);
            __builtin_amdgcn_global_load_lds((gas_ptr)(gV1 + sn), (las_ptr)(&Vl[nb][lo1]), 16, 0, 0);
        }

        // wave-uniform tile skip: any (t in [tw,tw+15], s in [s0,s0+31]) with s<=t and s>=t-WINDOW?
        if (s0 <= tw + 15 && s0 + 31 >= tw - WINDOW) {
            const u16* Kb = &Kl[buf][0];
            const u16* Vb = &Vl[buf][0];

            // S = Q K^T (two 16-key col tiles)
            floatx4 sacc[2] = {};
            #pragma unroll
            for (int nt = 0; nt < 2; nt++)
                #pragma unroll
                for (int kk = 0; kk < 4; kk++) {
                    int row = nt * 16 + ln;
                    short8 bfr = *(const short8*)(Kb + row * 128 + (((kk * 4 + quad) ^ ln) * 8));
                    sacc[nt] = __builtin_amdgcn_mfma_f32_16x16x32_bf16(qf[kk], bfr, sacc[nt], 0, 0, 0);
                }

            // softcap+exp (fixed-max streaming softmax: p = exp(logit), bounded by e^50)
            float p[2][4];
            bool full = (s0 + 31 <= tw) && (s0 >= tw + 15 - WINDOW);
            if (full) {
                #pragma unroll
                for (int nt = 0; nt < 2; nt++)
                    #pragma unroll
                    for (int r = 0; r < 4; r++)
                        p[nt][r] = softcap_exp(sacc[nt][r]);
            } else {
                #pragma unroll
                for (int nt = 0; nt < 2; nt++) {
                    int s = s0 + nt * 16 + ln;
                    #pragma unroll
                    for (int r = 0; r < 4; r++) {
                        int t = tw + quad * 4 + r;
                        bool good = (s <= t) && (s >= t - WINDOW);
                        float v = softcap_exp(sacc[nt][r]);
                        p[nt][r] = good ? v : 0.0f;
                    }
                }
            }

            // P -> LDS (C-layout), read back as A-fragment (wave-local; lgkmcnt only)
            #pragma unroll
            for (int nt = 0; nt < 2; nt++)
                #pragma unroll
                for (int r = 0; r < 4; r++)
                    Pl[w][quad * 4 + r][nt * 16 + ln] = f2bf(p[nt][r]);
            short8 pf = *(const short8*)(&Pl[w][ln][quad * 8]);

            // O += P V ; l += P 1
            #pragma unroll
            for (int dt = 0; dt < 8; dt++) {
                short8 vf = *(const short8*)(Vb + (dt * 16 + ln) * 32 + quad * 8);
                oacc[dt] = __builtin_amdgcn_mfma_f32_16x16x32_bf16(pf, vf, oacc[dt], 0, 0, 0);
            }
            oacc[8] = __builtin_amdgcn_mfma_f32_16x16x32_bf16(pf, ones, oacc[8], 0, 0, 0);
        }
        buf ^= 1;
    }

    // epilogue: normalize + store encoded bf16 (each lane owns rows quad*4+r at col ln; l in oacc[8])
    #pragma unroll
    for (int r = 0; r < 4; r++) {
        int t = tw + quad * 4 + r;
        float invl = __builtin_amdgcn_rcpf(oacc[8][r]);
        u16* dst = Enc + (((size_t)b * TT + t) * NH + h) * HD;
        #pragma unroll
        for (int dt = 0; dt < 8; dt++)
            dst[dt * 16 + ln] = f2bf(oacc[dt][r] * invl);
    }
}

extern "C" void kernel_launch(void* const* d_in, const int* in_sizes, int n_in,
                              void* d_out, int out_size, void* d_ws, size_t ws_size,
                              hipStream_t stream) {
    const float* x  = (const float*)d_in[0];
    const float* wq = (const float*)d_in[1];
    const float* wk = (const float*)d_in[2];
    const float* wv = (const float*)d_in[3];
    const float* wo = (const float*)d_in[4];
    float* out = (float*)d_out;

    char* ws = (char*)d_ws;
    size_t off = 0;
    auto alloc = [&](size_t bytes) -> void* {
        void* p = ws + off;
        off += (bytes + 255) & ~(size_t)255;
        return p;
    };
    u16* xb   = (u16*)alloc((size_t)BT * CC * 2);
    u16* wqT  = (u16*)alloc((size_t)CC * CC * 2);
    u16* wkvT = (u16*)alloc((size_t)(2*NKV*HD) * CC * 2);   // K rows 0-511, V rows 512-1023
    u16* woT  = (u16*)alloc((size_t)CC * CC * 2);
    u16* Qb   = (u16*)alloc((size_t)BT * NH * HD * 2);
    u16* KVb  = (u16*)alloc((size_t)BT * 2 * NKV * HD * 2); // [4096][1024]
    u16* VtT  = (u16*)alloc((size_t)BT * NKV * HD * 2);     // [B][NKV][HD][T]
    u16* Enc  = (u16*)alloc((size_t)BT * NH * HD * 2);

    // 1) casts / weight transposes
    cast_bf16_kernel<<<(BT * CC / 4 + 255) / 256, 256, 0, stream>>>(x, xb, BT * CC / 4);
    dim3 tb(32, 8);
    transpose_cast_f32_kernel<<<dim3(CC / 32, CC / 32), tb, 0, stream>>>(wq, wqT, CC, CC);
    transpose_cast_f32_kernel<<<dim3(NKV * HD / 32, CC / 32), tb, 0, stream>>>(wk, wkvT, CC, NKV * HD);
    transpose_cast_f32_kernel<<<dim3(NKV * HD / 32, CC / 32), tb, 0, stream>>>(wv, wkvT + (size_t)(NKV * HD) * CC, CC, NKV * HD);
    transpose_cast_f32_kernel<<<dim3(CC / 32, CC / 32), tb, 0, stream>>>(wo, woT, CC, CC);

    // 2) projections: Q (N=2048) and merged KV (N=1024)
    gemm128_kernel<false><<<dim3(CC / 128, BT / 128), 256, 0, stream>>>(xb, wqT, Qb, BT, CC, CC);
    gemm128_kernel<false><<<dim3(2 * NKV * HD / 128, BT / 128), 256, 0, stream>>>(xb, wkvT, KVb, BT, 2 * NKV * HD, CC);

    // 3) RoPE (scale folded into Q); K lives in first 512 cols of KVb rows (stride 1024)
    rope_kernel<<<BT * NH, HD, 0, stream>>>(Qb, NH, NH * HD, 0.08838834764831845f);
    rope_kernel<<<BT * NKV, HD, 0, stream>>>(KVb, NKV, 2 * NKV * HD, 1.0f);

    // 4) V -> V^T per batch: KVb rows [T][1024] cols 512.. -> [512][T]
    transpose_bf16_kernel<<<dim3(TT / 32, NKV * HD / 32, BB), tb, 0, stream>>>(
        KVb, VtT, TT, NKV * HD, 2 * NKV * HD, NKV * HD,
        (size_t)TT * 2 * NKV * HD, (size_t)NKV * HD * TT);

    // 5) flash attention
    attn_kernel<<<dim3(TT / 64, NH, BB), 256, 0, stream>>>(Qb, KVb, VtT, Enc);

    // 6) output projection (fp32 out)
    gemm128_kernel<true><<<dim3(CC / 128, BT / 128), 256, 0, stream>>>(Enc, woT, out, BT, CC, CC);
}